// Round 8
// baseline (221.674 us; speedup 1.0000x reference)
//
#include <hip/hip_runtime.h>

#define N_EDGES_C 1048576

typedef __attribute__((ext_vector_type(8))) __bf16 bf16x8;
typedef __attribute__((ext_vector_type(4))) __bf16 bf16x4;
typedef __attribute__((ext_vector_type(4))) float f32x4;

#define MFMA16(a,b,c) __builtin_amdgcn_mfma_f32_16x16x32_bf16((a),(b),(c),0,0,0)

__device__ __forceinline__ unsigned short f2bf(float f) {
  unsigned int u = __builtin_bit_cast(unsigned int, f);
  u = (u + 0x7fffu + ((u >> 16) & 1u)) >> 16;
  return (unsigned short)u;
}
__device__ __forceinline__ float bf2f(unsigned short h) {
  unsigned int u = ((unsigned int)h) << 16;
  return __builtin_bit_cast(float, u);
}

// ---------------- prep: bf16-transpose weights + fold BN + transpose readout W ----------------
__global__ void prep_kernel(const float* __restrict__ Wc0s, const float* __restrict__ Wc0n,
                            const float* __restrict__ Wc1s, const float* __restrict__ Wc1n,
                            const float* __restrict__ Wa,
                            const float* __restrict__ bc0, const float* __restrict__ g0,
                            const float* __restrict__ b0, const float* __restrict__ m0,
                            const float* __restrict__ v0,
                            const float* __restrict__ bc1, const float* __restrict__ g1,
                            const float* __restrict__ b1, const float* __restrict__ m1,
                            const float* __restrict__ v1,
                            const float* __restrict__ Wr0, const float* __restrict__ Wr1,
                            unsigned short* __restrict__ wbf, float* __restrict__ cst,
                            float* __restrict__ wr0t, float* __restrict__ wr1t) {
  int t = blockIdx.x * blockDim.x + threadIdx.x;
  if (t < 8192) {                       // 64x128 -> [d][f]
    int d = t >> 6, f = t & 63;
    wbf[t]        = f2bf(Wc0s[f * 128 + d]);
    wbf[8192 + t] = f2bf(Wc0n[f * 128 + d]);
  } else if (t < 24576) {               // 128x128 -> [d][k]
    int i = t - 8192;
    int d = i >> 7, k = i & 127;
    wbf[16384 + i] = f2bf(Wc1s[k * 128 + d]);
    wbf[32768 + i] = f2bf(Wc1n[k * 128 + d]);
    wbf[49152 + i] = f2bf(Wa[k * 128 + d]);
  } else if (t < 24704) {
    int d = t - 24576;
    float s0 = g0[d] * rsqrtf(v0[d] + 1e-5f);
    cst[d]       = s0;
    cst[128 + d] = (bc0[d] - m0[d]) * s0 + b0[d];
    float s1 = g1[d] * rsqrtf(v1[d] + 1e-5f);
    cst[256 + d] = s1;
    cst[384 + d] = (bc1[d] - m1[d]) * s1 + b1[d];
  } else if (t < 57472) {               // readout weights f32 transpose
    int i = t - 24704;
    int which = i >> 14;
    int k = i & 16383;
    int d = k >> 7, j = k & 127;
    float v = (which ? Wr1 : Wr0)[j * 128 + d];
    (which ? wr1t : wr0t)[k] = v;
  }
}

// ---------------- fused per-graph kernel: 1 block = 1 graph, 80KB LDS arena, 2 blocks/CU ----------------
// All GEMMs computed transposed: out^T[d][node] = W^T @ h^T with A = weights (global, k-contig),
// B = h node-major LDS (k-contig). Adj term: (Adj@V)^T = V^T @ Adj^T, B-frag = counts[dst][src]*inv[dst].
__global__ __launch_bounds__(512, 4)
void gnn_fused(const float* __restrict__ x, const float* __restrict__ mwt,
               const int* __restrict__ ei,
               const unsigned short* __restrict__ wbf, const float* __restrict__ cst,
               const float* __restrict__ ba,
               const float* __restrict__ wr0t, const float* __restrict__ br0,
               const float* __restrict__ wr1t, const float* __restrict__ br1,
               const float* __restrict__ Wout, const float* __restrict__ bout,
               float* __restrict__ out) {
  // 5 x 16KB slots. feature half = [128 node][64 d] bf16, 128B rows, swz ((node&7)<<4)
  //                 V half       = [64 d][128 node] bf16, 256B rows, swz ((d&7)<<4)
  __shared__ __align__(16) unsigned char arena[81920];
  unsigned short* S0  = (unsigned short*)(arena);            // V0h0 -> h1h0 -> p_h0
  unsigned short* S1  = (unsigned short*)(arena + 16384);    // V0h1 -> h1h1 -> p_h1
  unsigned short* S2  = (unsigned short*)(arena + 32768);    // sInv -> V1h0 -> h2h0
  unsigned char*  CNT = arena + 49152;                       // counts -> pool/sv1/temps
  unsigned short* S4  = (unsigned short*)(arena + 65536);    // x -> V1h1 -> h2h1
  float* S2f = (float*)S2;
  float* S3f = (float*)CNT;

  const int gb = blockIdx.x;
  const int t = threadIdx.x;
  const int lane = t & 63;
  const int w = t >> 6;
  const int c  = lane & 15;
  const int gq = lane >> 4;
  const int r0 = gq << 2;
  const int mt = w >> 2;        // d-tile 0..1 (32 rows)
  const int nn = w & 3;         // node-tile 0..3 (32 cols)
  const f32x4 zero = {0.f, 0.f, 0.f, 0.f};

  auto lk = [](float v) { return v > 0.f ? v : 0.01f * v; };
  auto ldW = [&](const unsigned short* Wt, int K, int d, int kb) -> bf16x8 {
    return *(const bf16x8*)(Wt + (d + c) * K + kb + gq * 8);
  };
  auto ldH = [&](const unsigned short* H, int nodeB, int kl) -> bf16x8 {
    int r = nodeB + c;
    int cb2 = (kl + gq * 8) * 2;
    return *(const bf16x8*)((const char*)H + r * 128 + (cb2 ^ ((r & 7) << 4)));
  };
  auto ldV = [&](const unsigned short* V, int dB, int nodek) -> bf16x8 {
    int r = dB + c;
    int cb2 = (nodek + gq * 8) * 2;
    return *(const bf16x8*)((const char*)V + r * 256 + (cb2 ^ ((r & 7) << 4)));
  };

  // ---- P0: zero counts; x -> S4 (node-major bf16)
  {
    unsigned int* c32 = (unsigned int*)CNT;
    for (int i = t; i < 4096; i += 512) c32[i] = 0u;
  }
  {
    const float4* xg = (const float4*)(x + (size_t)gb * 8192);
#pragma unroll
    for (int i = 0; i < 4; i++) {
      int vi = t + i * 512;
      float4 v = xg[vi];
      int node = vi >> 4;
      int f2 = (vi & 15) * 8;
      bf16x4 qv = {(__bf16)v.x, (__bf16)v.y, (__bf16)v.z, (__bf16)v.w};
      *(bf16x4*)((char*)S4 + node * 128 + (f2 ^ ((node & 7) << 4))) = qv;
    }
  }
  __syncthreads();

  // ---- P1: histogram counts[dst][src] (src-contig, swz ((dst&7)<<3))
  {
    int e = gb * 512 + t;
    int ls_ = ei[e] & 127;
    int ld_ = ei[N_EDGES_C + e] & 127;
    int cb = ls_ ^ ((ld_ & 7) << 3);
    int idx = ld_ * 128 + cb;
    atomicAdd((unsigned int*)(CNT + (idx & ~3)), 1u << ((idx & 3) * 8));
  }
  __syncthreads();

  // ---- P2: inv_deg (row sums of counts) -> S2f[0:128]
  {
    int row = t >> 2, qd = t & 3;
    const unsigned int* rp = (const unsigned int*)(CNT + row * 128) + qd * 8;
    int ssum = 0;
#pragma unroll
    for (int i = 0; i < 8; i++) {
      unsigned int v = rp[i];
      ssum += (int)(v & 0xff) + (int)((v >> 8) & 0xff) + (int)((v >> 16) & 0xff) + (int)(v >> 24);
    }
    ssum += __shfl_xor(ssum, 1);
    ssum += __shfl_xor(ssum, 2);
    if (qd == 0) S2f[row] = 1.f / (float)(ssum > 1 ? ssum : 1);
  }
  __syncthreads();

  const float inv0 = S2f[nn * 32 + c];
  const float inv1 = S2f[nn * 32 + 16 + c];

  auto ldAdj = [&](int noBase, int kb, float inv) -> bf16x8 {
    int m = noBase + c;
    int cc = (kb + gq * 8) ^ ((m & 7) << 3);
    const unsigned int* p = (const unsigned int*)(CNT + m * 128 + cc);
    unsigned int w0 = p[0], w1 = p[1];
    bf16x8 r;
#pragma unroll
    for (int i2 = 0; i2 < 4; i2++) {
      r[i2]     = (__bf16)((float)((w0 >> (8 * i2)) & 0xffu) * inv);
      r[4 + i2] = (__bf16)((float)((w1 >> (8 * i2)) & 0xffu) * inv);
    }
    return r;
  };
  auto gemmW = [&](const unsigned short* Wt, int K, int dBase, f32x4* a4,
                   int kb, const unsigned short* H, int kl) {
    bf16x8 A0 = ldW(Wt, K, dBase, kb);
    bf16x8 A1 = ldW(Wt, K, dBase + 16, kb);
    bf16x8 B0 = ldH(H, nn * 32, kl);
    bf16x8 B1 = ldH(H, nn * 32 + 16, kl);
    a4[0] = MFMA16(A0, B0, a4[0]);
    a4[1] = MFMA16(A0, B1, a4[1]);
    a4[2] = MFMA16(A1, B0, a4[2]);
    a4[3] = MFMA16(A1, B1, a4[3]);
  };
  auto gemmA = [&](const unsigned short* V, f32x4* a4, int kb) {
    bf16x8 A0 = ldV(V, mt * 32, kb);
    bf16x8 A1 = ldV(V, mt * 32 + 16, kb);
    bf16x8 B0 = ldAdj(nn * 32, kb, inv0);
    bf16x8 B1 = ldAdj(nn * 32 + 16, kb, inv1);
    a4[0] = MFMA16(A0, B0, a4[0]);
    a4[1] = MFMA16(A0, B1, a4[1]);
    a4[2] = MFMA16(A1, B0, a4[2]);
    a4[3] = MFMA16(A1, B1, a4[3]);
  };
  // V^T epilogue: quad 4x4 transpose -> node-contiguous b64 writes
  auto epiV = [&](unsigned short* V, f32x4* av) {
#pragma unroll
    for (int i = 0; i < 2; i++)
#pragma unroll
      for (int n = 0; n < 2; n++) {
        f32x4 v = av[i * 2 + n];
        float a0 = v[0], a1 = v[1], a2 = v[2], a3 = v[3];
        {
          bool lo = (lane & 1) == 0;
          float sA = lo ? a1 : a0, sB = lo ? a3 : a2;
          float rA = __shfl_xor(sA, 1), rB = __shfl_xor(sB, 1);
          if (lo) { a1 = rA; a3 = rB; } else { a0 = rA; a2 = rB; }
        }
        {
          bool lo = (lane & 2) == 0;
          float sA = lo ? a2 : a0, sB = lo ? a3 : a1;
          float rA = __shfl_xor(sA, 2), rB = __shfl_xor(sB, 2);
          if (lo) { a2 = rA; a3 = rB; } else { a0 = rA; a1 = rB; }
        }
        int dloc = mt * 32 + 16 * i + r0 + (lane & 3);
        int nodeB2 = (nn * 32 + 16 * n + ((lane >> 2) & 3) * 4) * 2;
        bf16x4 o = {(__bf16)a0, (__bf16)a1, (__bf16)a2, (__bf16)a3};
        *(bf16x4*)((char*)V + dloc * 256 + (nodeB2 ^ ((dloc & 7) << 4))) = o;
      }
  };

  f32x4 va[4], vb[4], ca[4], cb4[4];

  // ---- P3: V0h0 = W0n^T[0:64]@x^T -> S0
#pragma unroll
  for (int i = 0; i < 4; i++) va[i] = zero;
  gemmW(wbf + 8192, 64, mt * 32, va, 0, S4, 0);
  gemmW(wbf + 8192, 64, mt * 32, va, 32, S4, 32);
  epiV(S0, va);
  __syncthreads();

  // ---- P4: conv0p0 = W0s^T[0:64]@x^T + V0h0@AdjB ; V0h1 = W0n^T[64:128]@x^T
#pragma unroll
  for (int i = 0; i < 4; i++) { ca[i] = zero; vb[i] = zero; }
  gemmW(wbf, 64, mt * 32, ca, 0, S4, 0);
  gemmW(wbf, 64, mt * 32, ca, 32, S4, 32);
  for (int kb = 0; kb < 128; kb += 32) gemmA(S0, ca, kb);
  gemmW(wbf + 8192, 64, 64 + mt * 32, vb, 0, S4, 0);
  gemmW(wbf + 8192, 64, 64 + mt * 32, vb, 32, S4, 32);
  __syncthreads();

  // ---- P5: BN0+leaky -> h1h0 (S0); epiV(V0h1) -> S1
#pragma unroll
  for (int i = 0; i < 2; i++) {
    int dB = mt * 32 + 16 * i + r0;
    float4 mul4 = *(const float4*)(cst + dB);
    float4 add4 = *(const float4*)(cst + 128 + dB);
#pragma unroll
    for (int n = 0; n < 2; n++) {
      f32x4 v = ca[i * 2 + n];
      int node = nn * 32 + 16 * n + c;
      bf16x4 o = {(__bf16)lk(v[0] * mul4.x + add4.x), (__bf16)lk(v[1] * mul4.y + add4.y),
                  (__bf16)lk(v[2] * mul4.z + add4.z), (__bf16)lk(v[3] * mul4.w + add4.w)};
      *(bf16x4*)((char*)S0 + node * 128 + ((2 * dB) ^ ((node & 7) << 4))) = o;
    }
  }
  epiV(S1, vb);
  __syncthreads();

  // ---- P6: conv0p1 = W0s^T[64:128]@x^T + V0h1@AdjB
#pragma unroll
  for (int i = 0; i < 4; i++) ca[i] = zero;
  gemmW(wbf, 64, 64 + mt * 32, ca, 0, S4, 0);
  gemmW(wbf, 64, 64 + mt * 32, ca, 32, S4, 32);
  for (int kb = 0; kb < 128; kb += 32) gemmA(S1, ca, kb);
  __syncthreads();

  // ---- P7: BN0+leaky -> h1h1 (S1)
#pragma unroll
  for (int i = 0; i < 2; i++) {
    int dB = mt * 32 + 16 * i + r0;
    float4 mul4 = *(const float4*)(cst + 64 + dB);
    float4 add4 = *(const float4*)(cst + 192 + dB);
#pragma unroll
    for (int n = 0; n < 2; n++) {
      f32x4 v = ca[i * 2 + n];
      int node = nn * 32 + 16 * n + c;
      bf16x4 o = {(__bf16)lk(v[0] * mul4.x + add4.x), (__bf16)lk(v[1] * mul4.y + add4.y),
                  (__bf16)lk(v[2] * mul4.z + add4.z), (__bf16)lk(v[3] * mul4.w + add4.w)};
      *(bf16x4*)((char*)S1 + node * 128 + ((2 * dB) ^ ((node & 7) << 4))) = o;
    }
  }
  __syncthreads();

  // ---- P8: V1 both halves = W1n^T@h1^T
#pragma unroll
  for (int i = 0; i < 4; i++) { va[i] = zero; vb[i] = zero; }
  for (int kb = 0; kb < 128; kb += 32) {
    const unsigned short* H = (kb < 64) ? S0 : S1;
    int kl = kb & 63;
    gemmW(wbf + 32768, 128, mt * 32, va, kb, H, kl);
    gemmW(wbf + 32768, 128, 64 + mt * 32, vb, kb, H, kl);
  }
  __syncthreads();

  // ---- P9: epiV -> S2 (sInv dead), S4 (x dead)
  epiV(S2, va);
  epiV(S4, vb);
  __syncthreads();

  // ---- P10: conv1 both halves = W1s^T@h1^T + V1@AdjB
#pragma unroll
  for (int i = 0; i < 4; i++) { ca[i] = zero; cb4[i] = zero; }
  for (int kb = 0; kb < 128; kb += 32) {
    const unsigned short* H = (kb < 64) ? S0 : S1;
    int kl = kb & 63;
    gemmW(wbf + 16384, 128, mt * 32, ca, kb, H, kl);
    gemmW(wbf + 16384, 128, 64 + mt * 32, cb4, kb, H, kl);
  }
  for (int kb = 0; kb < 128; kb += 32) {
    gemmA(S2, ca, kb);
    gemmA(S4, cb4, kb);
  }
  __syncthreads();

  // ---- P11: zero pool/sv1/sOut in CNT slot (counts dead)
  if (t < 256) S3f[t] = 0.f;
  if (t == 256) S3f[512] = 0.f;
  __syncthreads();

  // ---- P12: BN1+leaky+mw -> h2 (S2,S4) + pool
  {
    float mw0 = mwt[(size_t)gb * 128 + nn * 32 + c];
    float mw1 = mwt[(size_t)gb * 128 + nn * 32 + 16 + c];
#pragma unroll
    for (int hf = 0; hf < 2; hf++) {
      f32x4* A = hf ? cb4 : ca;
      unsigned short* H = hf ? S4 : S2;
      int dOff = hf * 64;
#pragma unroll
      for (int i = 0; i < 2; i++) {
        int dB = mt * 32 + 16 * i + r0;
        float4 mul4 = *(const float4*)(cst + 256 + dOff + dB);
        float4 add4 = *(const float4*)(cst + 384 + dOff + dB);
        f32x4 v0v = A[i * 2 + 0], v1v = A[i * 2 + 1];
        float y0 = lk(v0v[0] * mul4.x + add4.x) * mw0;
        float y1 = lk(v0v[1] * mul4.y + add4.y) * mw0;
        float y2 = lk(v0v[2] * mul4.z + add4.z) * mw0;
        float y3 = lk(v0v[3] * mul4.w + add4.w) * mw0;
        float z0 = lk(v1v[0] * mul4.x + add4.x) * mw1;
        float z1 = lk(v1v[1] * mul4.y + add4.y) * mw1;
        float z2 = lk(v1v[2] * mul4.z + add4.z) * mw1;
        float z3 = lk(v1v[3] * mul4.w + add4.w) * mw1;
        int nodeA = nn * 32 + c;
        int nodeB = nn * 32 + 16 + c;
        bf16x4 oa = {(__bf16)y0, (__bf16)y1, (__bf16)y2, (__bf16)y3};
        bf16x4 ob = {(__bf16)z0, (__bf16)z1, (__bf16)z2, (__bf16)z3};
        *(bf16x4*)((char*)H + nodeA * 128 + ((2 * dB) ^ ((nodeA & 7) << 4))) = oa;
        *(bf16x4*)((char*)H + nodeB * 128 + ((2 * dB) ^ ((nodeB & 7) << 4))) = ob;
        float s0 = y0 + z0, s1 = y1 + z1, s2 = y2 + z2, s3 = y3 + z3;
#pragma unroll
        for (int m = 1; m < 16; m <<= 1) {
          s0 += __shfl_xor(s0, m); s1 += __shfl_xor(s1, m);
          s2 += __shfl_xor(s2, m); s3 += __shfl_xor(s3, m);
        }
        if (c == 0) {
          atomicAdd(&S3f[dOff + dB + 0], s0);
          atomicAdd(&S3f[dOff + dB + 1], s1);
          atomicAdd(&S3f[dOff + dB + 2], s2);
          atomicAdd(&S3f[dOff + dB + 3], s3);
        }
      }
    }
  }
  __syncthreads();

  // ---- P13: p = Wa^T@h2^T (both halves)
#pragma unroll
  for (int i = 0; i < 4; i++) { va[i] = zero; vb[i] = zero; }
  for (int kb = 0; kb < 128; kb += 32) {
    const unsigned short* H = (kb < 64) ? S2 : S4;
    int kl = kb & 63;
    gemmW(wbf + 49152, 128, mt * 32, va, kb, H, kl);
    gemmW(wbf + 49152, 128, 64 + mt * 32, vb, kb, H, kl);
  }
  __syncthreads();

  // ---- P14: +ba, leaky -> p halves (S0, S1)  [h1 dead]
#pragma unroll
  for (int hf = 0; hf < 2; hf++) {
    f32x4* A = hf ? vb : va;
    unsigned short* H = hf ? S1 : S0;
#pragma unroll
    for (int i = 0; i < 2; i++) {
      int dB = mt * 32 + 16 * i + r0;
      float4 ba4 = *(const float4*)(ba + hf * 64 + dB);
#pragma unroll
      for (int n = 0; n < 2; n++) {
        f32x4 v = A[i * 2 + n];
        int node = nn * 32 + 16 * n + c;
        bf16x4 o = {(__bf16)lk(v[0] + ba4.x), (__bf16)lk(v[1] + ba4.y),
                    (__bf16)lk(v[2] + ba4.z), (__bf16)lk(v[3] + ba4.w)};
        *(bf16x4*)((char*)H + node * 128 + ((2 * dB) ^ ((node & 7) << 4))) = o;
      }
    }
  }
  __syncthreads();

  // ---- P15: pair = sigmoid(pA@pB^T) -> row/col sums only (sv1 @ S3f+128)
  {
    f32x4 acc2[2] = {zero, zero};
    for (int kb = 0; kb < 128; kb += 32) {
      const unsigned short* H = (kb < 64) ? S0 : S1;
      int kl = kb & 63;
#pragma unroll
      for (int i = 0; i < 2; i++) {
        int T = w * 2 + i;
        bf16x8 a = ldH(H, (T >> 2) * 16, kl);
        bf16x8 b = ldH(H, 64 + (T & 3) * 16, kl);
        acc2[i] = MFMA16(a, b, acc2[i]);
      }
    }
    float* sv1 = S3f + 128;
#pragma unroll
    for (int i = 0; i < 2; i++) {
      int T = w * 2 + i, mb = (T >> 2) * 16, nb = (T & 3) * 16;
      float s0 = 1.f / (1.f + __expf(-acc2[i][0]));
      float s1 = 1.f / (1.f + __expf(-acc2[i][1]));
      float s2 = 1.f / (1.f + __expf(-acc2[i][2]));
      float s3 = 1.f / (1.f + __expf(-acc2[i][3]));
      atomicAdd(&sv1[64 + nb + c], s0 + s1 + s2 + s3);
#pragma unroll
      for (int m = 1; m < 16; m <<= 1) {
        s0 += __shfl_xor(s0, m); s1 += __shfl_xor(s1, m);
        s2 += __shfl_xor(s2, m); s3 += __shfl_xor(s3, m);
      }
      if (c < 4) {
        float v = c == 0 ? s0 : (c == 1 ? s1 : (c == 2 ? s2 : s3));
        atomicAdd(&sv1[mb + r0 + c], v);
      }
    }
  }
  __syncthreads();

  // ---- P16: delta pool: pool[d] += sum_node u[node]*p[node][d]
  {
    int d = t & 127, qd = t >> 7;
    const unsigned short* H = (d < 64) ? S0 : S1;
    int dl2 = (d & 63) * 2;
    float s = 0.f;
#pragma unroll
    for (int i = 0; i < 32; i++) {
      int node = qd * 32 + i;
      float u = S3f[128 + node];
      unsigned short pv = *(const unsigned short*)((const char*)H + node * 128 + (dl2 ^ ((node & 7) << 4)));
      s += u * bf2f(pv);
    }
    atomicAdd(&S3f[d], s);
  }
  __syncthreads();

  // ---- P17: readout
  if (t < 128) S3f[t] *= (1.f / 128.f);
  __syncthreads();
  {
    int d = t >> 2, qd = t & 3;
    const float* row = wr0t + d * 128 + qd * 32;
    float s = 0.f;
#pragma unroll
    for (int j2 = 0; j2 < 32; j2++) s += S3f[qd * 32 + j2] * row[j2];
    s += __shfl_xor(s, 1);
    s += __shfl_xor(s, 2);
    if (qd == 0) { s += br0[d]; S3f[256 + d] = lk(s); }
  }
  __syncthreads();
  {
    int d = t >> 2, qd = t & 3;
    const float* row = wr1t + d * 128 + qd * 32;
    float s = 0.f;
#pragma unroll
    for (int j2 = 0; j2 < 32; j2++) s += S3f[256 + qd * 32 + j2] * row[j2];
    s += __shfl_xor(s, 1);
    s += __shfl_xor(s, 2);
    if (qd == 0) { s += br1[d]; S3f[384 + d] = lk(s); }
  }
  __syncthreads();
  if (t < 128) atomicAdd(&S3f[512], S3f[384 + t] * Wout[t]);
  __syncthreads();
  if (t == 0) out[gb] = S3f[512] + bout[0];
}

extern "C" void kernel_launch(void* const* d_in, const int* in_sizes, int n_in,
                              void* d_out, int out_size, void* d_ws, size_t ws_size,
                              hipStream_t stream) {
  const float* x     = (const float*)d_in[0];
  const float* mwt   = (const float*)d_in[1];
  const float* Wc0s  = (const float*)d_in[2];
  const float* Wc0n  = (const float*)d_in[3];
  const float* bc0   = (const float*)d_in[4];
  const float* g0    = (const float*)d_in[5];
  const float* b0    = (const float*)d_in[6];
  const float* m0    = (const float*)d_in[7];
  const float* v0    = (const float*)d_in[8];
  const float* Wc1s  = (const float*)d_in[9];
  const float* Wc1n  = (const float*)d_in[10];
  const float* bc1   = (const float*)d_in[11];
  const float* g1    = (const float*)d_in[12];
  const float* b1    = (const float*)d_in[13];
  const float* m1    = (const float*)d_in[14];
  const float* v1    = (const float*)d_in[15];
  const float* Wa    = (const float*)d_in[16];
  const float* ba    = (const float*)d_in[17];
  const float* Wr0   = (const float*)d_in[18];
  const float* br0   = (const float*)d_in[19];
  const float* Wr1   = (const float*)d_in[20];
  const float* br1   = (const float*)d_in[21];
  const float* Wout  = (const float*)d_in[22];
  const float* bout  = (const float*)d_in[23];
  const int*   ei    = (const int*)d_in[24];

  unsigned short* wbf = (unsigned short*)d_ws;                 // 131072 B
  float* cst  = (float*)((char*)d_ws + 131072);                // 2048 B
  float* wr0t = (float*)((char*)d_ws + 133120);                // 65536 B
  float* wr1t = (float*)((char*)d_ws + 198656);                // 65536 B

  prep_kernel<<<dim3(225), dim3(256), 0, stream>>>(Wc0s, Wc0n, Wc1s, Wc1n, Wa,
                                                   bc0, g0, b0, m0, v0,
                                                   bc1, g1, b1, m1, v1,
                                                   Wr0, Wr1, wbf, cst, wr0t, wr1t);
  gnn_fused<<<dim3(2048), dim3(512), 0, stream>>>(x, mwt, ei, wbf, cst, ba,
                                                  wr0t, br0, wr1t, br1, Wout, bout,
                                                  (float*)d_out);
}

// Round 9
// 213.122 us; speedup vs baseline: 1.0401x; 1.0401x over previous
//
#include <hip/hip_runtime.h>

#define N_EDGES_C 1048576

typedef __attribute__((ext_vector_type(8))) __bf16 bf16x8;
typedef __attribute__((ext_vector_type(4))) __bf16 bf16x4;
typedef __attribute__((ext_vector_type(4))) float f32x4;

#define MFMA16(a,b,c) __builtin_amdgcn_mfma_f32_16x16x32_bf16((a),(b),(c),0,0,0)

// LDS-visible barrier that does NOT drain vmcnt: global->reg prefetch stays in flight.
#define BARRIER() do { asm volatile("s_waitcnt lgkmcnt(0)" ::: "memory"); \
                       __builtin_amdgcn_s_barrier(); \
                       asm volatile("" ::: "memory"); } while (0)

__device__ __forceinline__ unsigned short f2bf(float f) {
  unsigned int u = __builtin_bit_cast(unsigned int, f);
  u = (u + 0x7fffu + ((u >> 16) & 1u)) >> 16;
  return (unsigned short)u;
}
__device__ __forceinline__ float bf2f(unsigned short h) {
  unsigned int u = ((unsigned int)h) << 16;
  return __builtin_bit_cast(float, u);
}

// ---------------- prep: bf16-transpose weights + fold BN + transpose readout W ----------------
__global__ void prep_kernel(const float* __restrict__ Wc0s, const float* __restrict__ Wc0n,
                            const float* __restrict__ Wc1s, const float* __restrict__ Wc1n,
                            const float* __restrict__ Wa,
                            const float* __restrict__ bc0, const float* __restrict__ g0,
                            const float* __restrict__ b0, const float* __restrict__ m0,
                            const float* __restrict__ v0,
                            const float* __restrict__ bc1, const float* __restrict__ g1,
                            const float* __restrict__ b1, const float* __restrict__ m1,
                            const float* __restrict__ v1,
                            const float* __restrict__ Wr0, const float* __restrict__ Wr1,
                            unsigned short* __restrict__ wbf, float* __restrict__ cst,
                            float* __restrict__ wr0t, float* __restrict__ wr1t) {
  int t = blockIdx.x * blockDim.x + threadIdx.x;
  if (t < 8192) {                       // 64x128 -> [d][f]
    int d = t >> 6, f = t & 63;
    wbf[t]        = f2bf(Wc0s[f * 128 + d]);
    wbf[8192 + t] = f2bf(Wc0n[f * 128 + d]);
  } else if (t < 24576) {               // 128x128 -> [d][k]
    int i = t - 8192;
    int d = i >> 7, k = i & 127;
    wbf[16384 + i] = f2bf(Wc1s[k * 128 + d]);
    wbf[32768 + i] = f2bf(Wc1n[k * 128 + d]);
    wbf[49152 + i] = f2bf(Wa[k * 128 + d]);
  } else if (t < 24704) {
    int d = t - 24576;
    float s0 = g0[d] * rsqrtf(v0[d] + 1e-5f);
    cst[d]       = s0;
    cst[128 + d] = (bc0[d] - m0[d]) * s0 + b0[d];
    float s1 = g1[d] * rsqrtf(v1[d] + 1e-5f);
    cst[256 + d] = s1;
    cst[384 + d] = (bc1[d] - m1[d]) * s1 + b1[d];
  } else if (t < 57472) {               // readout weights f32 transpose
    int i = t - 24704;
    int which = i >> 14;
    int k = i & 16383;
    int d = k >> 7, j = k & 127;
    float v = (which ? Wr1 : Wr0)[j * 128 + d];
    (which ? wr1t : wr0t)[k] = v;
  }
}

// ---------------- fused per-graph kernel: 1 block = 1 graph, 80KB LDS arena, 2 blocks/CU ----------------
__global__ __launch_bounds__(512, 4)
void gnn_fused(const float* __restrict__ x, const float* __restrict__ mwt,
               const int* __restrict__ ei,
               const unsigned short* __restrict__ wbf, const float* __restrict__ cst,
               const float* __restrict__ ba,
               const float* __restrict__ wr0t, const float* __restrict__ br0,
               const float* __restrict__ wr1t, const float* __restrict__ br1,
               const float* __restrict__ Wout, const float* __restrict__ bout,
               float* __restrict__ out) {
  __shared__ __align__(16) unsigned char arena[81920];
  unsigned short* S0  = (unsigned short*)(arena);            // V0h0 -> h1h0 -> p_h0
  unsigned short* S1  = (unsigned short*)(arena + 16384);    // V0h1 -> h1h1 -> p_h1
  unsigned short* S2  = (unsigned short*)(arena + 32768);    // sInv -> V1h0 -> h2h0
  unsigned char*  CNT = arena + 49152;                       // counts -> pool/sv1/temps
  unsigned short* S4  = (unsigned short*)(arena + 65536);    // x -> V1h1 -> h2h1
  float* S2f = (float*)S2;
  float* S3f = (float*)CNT;

  const int gb = blockIdx.x;
  const int t = threadIdx.x;
  const int lane = t & 63;
  const int w = t >> 6;
  const int c  = lane & 15;
  const int gq = lane >> 4;
  const int r0 = gq << 2;
  const int mt = w >> 2;        // d-tile 0..1
  const int nn = w & 3;         // node-tile 0..3
  const f32x4 zero = {0.f, 0.f, 0.f, 0.f};

  auto lk = [](float v) { return v > 0.f ? v : 0.01f * v; };
  auto ldWg = [&](const unsigned short* Wt, int K, int dd, int kb) -> bf16x8 {
    return *(const bf16x8*)(Wt + (dd + c) * K + kb + gq * 8);
  };
  auto ldH = [&](const unsigned short* H, int nodeB, int kl) -> bf16x8 {
    int r = nodeB + c;
    int cb2 = (kl + gq * 8) * 2;
    return *(const bf16x8*)((const char*)H + r * 128 + (cb2 ^ ((r & 7) << 4)));
  };
  auto ldV = [&](const unsigned short* V, int dB, int nodek) -> bf16x8 {
    int r = dB + c;
    int cb2 = (nodek + gq * 8) * 2;
    return *(const bf16x8*)((const char*)V + r * 256 + (cb2 ^ ((r & 7) << 4)));
  };
  // A-prefetched GEMM: acc += A([32d]x[64k]) @ H-slot (k-local 0..63)
  auto gemmPF = [&](bf16x8 a00, bf16x8 a10, bf16x8 a01, bf16x8 a11,
                    const unsigned short* H, f32x4* a4) {
    bf16x8 b0 = ldH(H, nn * 32, 0), b1 = ldH(H, nn * 32 + 16, 0);
    a4[0] = MFMA16(a00, b0, a4[0]);
    a4[1] = MFMA16(a00, b1, a4[1]);
    a4[2] = MFMA16(a10, b0, a4[2]);
    a4[3] = MFMA16(a10, b1, a4[3]);
    b0 = ldH(H, nn * 32, 32); b1 = ldH(H, nn * 32 + 16, 32);
    a4[0] = MFMA16(a01, b0, a4[0]);
    a4[1] = MFMA16(a01, b1, a4[1]);
    a4[2] = MFMA16(a11, b0, a4[2]);
    a4[3] = MFMA16(a11, b1, a4[3]);
  };

  // ==== P0: issue first A-set (W0n d-lo); zero counts; x -> S4 ====
  bf16x8 A00 = ldWg(wbf + 8192, 64, mt * 32, 0);
  bf16x8 A10 = ldWg(wbf + 8192, 64, mt * 32 + 16, 0);
  bf16x8 A01 = ldWg(wbf + 8192, 64, mt * 32, 32);
  bf16x8 A11 = ldWg(wbf + 8192, 64, mt * 32 + 16, 32);
  int els, eld;
  {
    int e = gb * 512 + t;
    els = ei[e] & 127;
    eld = ei[N_EDGES_C + e] & 127;
  }
  {
    unsigned int* c32 = (unsigned int*)CNT;
    for (int i = t; i < 4096; i += 512) c32[i] = 0u;
  }
  {
    const float4* xg = (const float4*)(x + (size_t)gb * 8192);
#pragma unroll
    for (int i = 0; i < 4; i++) {
      int vi = t + i * 512;
      float4 v = xg[vi];
      int node = vi >> 4;
      int f2 = (vi & 15) * 8;
      bf16x4 qv = {(__bf16)v.x, (__bf16)v.y, (__bf16)v.z, (__bf16)v.w};
      *(bf16x4*)((char*)S4 + node * 128 + (f2 ^ ((node & 7) << 4))) = qv;
    }
  }
  BARRIER();

  // ==== P1: histogram counts[dst][src] ====
  {
    int cb = els ^ ((eld & 7) << 3);
    int idx = eld * 128 + cb;
    atomicAdd((unsigned int*)(CNT + (idx & ~3)), 1u << ((idx & 3) * 8));
  }
  BARRIER();

  // ==== P2: inv_deg -> S2f[0:128] ====
  {
    int row = t >> 2, qd = t & 3;
    const unsigned int* rp = (const unsigned int*)(CNT + row * 128) + qd * 8;
    int ssum = 0;
#pragma unroll
    for (int i = 0; i < 8; i++) {
      unsigned int v = rp[i];
      ssum += (int)(v & 0xff) + (int)((v >> 8) & 0xff) + (int)((v >> 16) & 0xff) + (int)(v >> 24);
    }
    ssum += __shfl_xor(ssum, 1);
    ssum += __shfl_xor(ssum, 2);
    if (qd == 0) S2f[row] = 1.f / (float)(ssum > 1 ? ssum : 1);
  }
  BARRIER();

  const float inv0 = S2f[nn * 32 + c];
  const float inv1 = S2f[nn * 32 + 16 + c];

  auto ldAdj = [&](int noBase, int kb, float inv) -> bf16x8 {
    int m = noBase + c;
    int cc = (kb + gq * 8) ^ ((m & 7) << 3);
    const unsigned int* p = (const unsigned int*)(CNT + m * 128 + cc);
    unsigned int w0 = p[0], w1 = p[1];
    bf16x8 r;
#pragma unroll
    for (int i2 = 0; i2 < 4; i2++) {
      r[i2]     = (__bf16)((float)((w0 >> (8 * i2)) & 0xffu) * inv);
      r[4 + i2] = (__bf16)((float)((w1 >> (8 * i2)) & 0xffu) * inv);
    }
    return r;
  };
  auto gemmA = [&](const unsigned short* V, f32x4* a4, int kb) {
    bf16x8 A0 = ldV(V, mt * 32, kb);
    bf16x8 A1 = ldV(V, mt * 32 + 16, kb);
    bf16x8 B0 = ldAdj(nn * 32, kb, inv0);
    bf16x8 B1 = ldAdj(nn * 32 + 16, kb, inv1);
    a4[0] = MFMA16(A0, B0, a4[0]);
    a4[1] = MFMA16(A0, B1, a4[1]);
    a4[2] = MFMA16(A1, B0, a4[2]);
    a4[3] = MFMA16(A1, B1, a4[3]);
  };
  auto epiV = [&](unsigned short* V, f32x4* av) {
#pragma unroll
    for (int i = 0; i < 2; i++)
#pragma unroll
      for (int n = 0; n < 2; n++) {
        f32x4 v = av[i * 2 + n];
        float a0 = v[0], a1 = v[1], a2 = v[2], a3 = v[3];
        {
          bool lo = (lane & 1) == 0;
          float sA = lo ? a1 : a0, sB = lo ? a3 : a2;
          float rA = __shfl_xor(sA, 1), rB = __shfl_xor(sB, 1);
          if (lo) { a1 = rA; a3 = rB; } else { a0 = rA; a2 = rB; }
        }
        {
          bool lo = (lane & 2) == 0;
          float sA = lo ? a2 : a0, sB = lo ? a3 : a1;
          float rA = __shfl_xor(sA, 2), rB = __shfl_xor(sB, 2);
          if (lo) { a2 = rA; a3 = rB; } else { a0 = rA; a1 = rB; }
        }
        int dloc = mt * 32 + 16 * i + r0 + (lane & 3);
        int nodeB2 = (nn * 32 + 16 * n + ((lane >> 2) & 3) * 4) * 2;
        bf16x4 o = {(__bf16)a0, (__bf16)a1, (__bf16)a2, (__bf16)a3};
        *(bf16x4*)((char*)V + dloc * 256 + (nodeB2 ^ ((dloc & 7) << 4))) = o;
      }
  };

  f32x4 va[4], vb[4], ca[4], cb4[4];

  // ==== P3: V0h0 = W0n_dlo @ x; issue W0s_dlo; epiV -> S0 ====
#pragma unroll
  for (int i = 0; i < 4; i++) va[i] = zero;
  gemmPF(A00, A10, A01, A11, S4, va);
  A00 = ldWg(wbf, 64, mt * 32, 0);
  A10 = ldWg(wbf, 64, mt * 32 + 16, 0);
  A01 = ldWg(wbf, 64, mt * 32, 32);
  A11 = ldWg(wbf, 64, mt * 32 + 16, 32);
  epiV(S0, va);
  BARRIER();

  // ==== P4: ca = W0s_dlo@x; issue W0n_dhi; ca += Adj@V0h0; vb = W0n_dhi@x; issue W0s_dhi ====
#pragma unroll
  for (int i = 0; i < 4; i++) { ca[i] = zero; vb[i] = zero; }
  gemmPF(A00, A10, A01, A11, S4, ca);
  A00 = ldWg(wbf + 8192, 64, 64 + mt * 32, 0);
  A10 = ldWg(wbf + 8192, 64, 64 + mt * 32 + 16, 0);
  A01 = ldWg(wbf + 8192, 64, 64 + mt * 32, 32);
  A11 = ldWg(wbf + 8192, 64, 64 + mt * 32 + 16, 32);
  for (int kb = 0; kb < 128; kb += 32) gemmA(S0, ca, kb);
  gemmPF(A00, A10, A01, A11, S4, vb);
  A00 = ldWg(wbf, 64, 64 + mt * 32, 0);
  A10 = ldWg(wbf, 64, 64 + mt * 32 + 16, 0);
  A01 = ldWg(wbf, 64, 64 + mt * 32, 32);
  A11 = ldWg(wbf, 64, 64 + mt * 32 + 16, 32);
  BARRIER();

  // ==== P5: BN0(ca) -> h1h0 (S0); epiV(vb) -> S1 ====
#pragma unroll
  for (int i = 0; i < 2; i++) {
    int dB = mt * 32 + 16 * i + r0;
    float4 mul4 = *(const float4*)(cst + dB);
    float4 add4 = *(const float4*)(cst + 128 + dB);
#pragma unroll
    for (int n = 0; n < 2; n++) {
      f32x4 v = ca[i * 2 + n];
      int node = nn * 32 + 16 * n + c;
      bf16x4 o = {(__bf16)lk(v[0] * mul4.x + add4.x), (__bf16)lk(v[1] * mul4.y + add4.y),
                  (__bf16)lk(v[2] * mul4.z + add4.z), (__bf16)lk(v[3] * mul4.w + add4.w)};
      *(bf16x4*)((char*)S0 + node * 128 + ((2 * dB) ^ ((node & 7) << 4))) = o;
    }
  }
  epiV(S1, vb);
  BARRIER();

  // ==== P6: ca = W0s_dhi@x + Adj@V0h1; issue W1n_dlo_klo ====
#pragma unroll
  for (int i = 0; i < 4; i++) ca[i] = zero;
  gemmPF(A00, A10, A01, A11, S4, ca);
  A00 = ldWg(wbf + 32768, 128, mt * 32, 0);
  A10 = ldWg(wbf + 32768, 128, mt * 32 + 16, 0);
  A01 = ldWg(wbf + 32768, 128, mt * 32, 32);
  A11 = ldWg(wbf + 32768, 128, mt * 32 + 16, 32);
  for (int kb = 0; kb < 128; kb += 32) gemmA(S1, ca, kb);
  BARRIER();

  // ==== P7: BN0 -> h1h1 (S1) ====
#pragma unroll
  for (int i = 0; i < 2; i++) {
    int dB = mt * 32 + 16 * i + r0;
    float4 mul4 = *(const float4*)(cst + 64 + dB);
    float4 add4 = *(const float4*)(cst + 192 + dB);
#pragma unroll
    for (int n = 0; n < 2; n++) {
      f32x4 v = ca[i * 2 + n];
      int node = nn * 32 + 16 * n + c;
      bf16x4 o = {(__bf16)lk(v[0] * mul4.x + add4.x), (__bf16)lk(v[1] * mul4.y + add4.y),
                  (__bf16)lk(v[2] * mul4.z + add4.z), (__bf16)lk(v[3] * mul4.w + add4.w)};
      *(bf16x4*)((char*)S1 + node * 128 + ((2 * dB) ^ ((node & 7) << 4))) = o;
    }
  }
  BARRIER();

  // ==== P8: V1 = W1n@h1 (both d-halves, K=128); epiV -> S2/S4 (x, sInv dead) ====
#pragma unroll
  for (int i = 0; i < 4; i++) { va[i] = zero; vb[i] = zero; }
  gemmPF(A00, A10, A01, A11, S0, va);             // d-lo, k 0-63
  A00 = ldWg(wbf + 32768, 128, 64 + mt * 32, 0);  // issue d-hi k-lo
  A10 = ldWg(wbf + 32768, 128, 64 + mt * 32 + 16, 0);
  A01 = ldWg(wbf + 32768, 128, 64 + mt * 32, 32);
  A11 = ldWg(wbf + 32768, 128, 64 + mt * 32 + 16, 32);
  gemmPF(A00, A10, A01, A11, S0, vb);
  A00 = ldWg(wbf + 32768, 128, mt * 32, 64);      // issue d-lo k-hi
  A10 = ldWg(wbf + 32768, 128, mt * 32 + 16, 64);
  A01 = ldWg(wbf + 32768, 128, mt * 32, 96);
  A11 = ldWg(wbf + 32768, 128, mt * 32 + 16, 96);
  gemmPF(A00, A10, A01, A11, S1, va);
  A00 = ldWg(wbf + 32768, 128, 64 + mt * 32, 64); // issue d-hi k-hi
  A10 = ldWg(wbf + 32768, 128, 64 + mt * 32 + 16, 64);
  A01 = ldWg(wbf + 32768, 128, 64 + mt * 32, 96);
  A11 = ldWg(wbf + 32768, 128, 64 + mt * 32 + 16, 96);
  gemmPF(A00, A10, A01, A11, S1, vb);
  A00 = ldWg(wbf + 16384, 128, mt * 32, 0);       // issue W1s d-lo k-lo (for P10)
  A10 = ldWg(wbf + 16384, 128, mt * 32 + 16, 0);
  A01 = ldWg(wbf + 16384, 128, mt * 32, 32);
  A11 = ldWg(wbf + 16384, 128, mt * 32 + 16, 32);
  epiV(S2, va);
  epiV(S4, vb);
  BARRIER();

  // ==== P10: conv1 = W1s@h1 + Adj@V1 (both halves) ====
#pragma unroll
  for (int i = 0; i < 4; i++) { ca[i] = zero; cb4[i] = zero; }
  gemmPF(A00, A10, A01, A11, S0, ca);
  A00 = ldWg(wbf + 16384, 128, 64 + mt * 32, 0);
  A10 = ldWg(wbf + 16384, 128, 64 + mt * 32 + 16, 0);
  A01 = ldWg(wbf + 16384, 128, 64 + mt * 32, 32);
  A11 = ldWg(wbf + 16384, 128, 64 + mt * 32 + 16, 32);
  gemmPF(A00, A10, A01, A11, S0, cb4);
  A00 = ldWg(wbf + 16384, 128, mt * 32, 64);
  A10 = ldWg(wbf + 16384, 128, mt * 32 + 16, 64);
  A01 = ldWg(wbf + 16384, 128, mt * 32, 96);
  A11 = ldWg(wbf + 16384, 128, mt * 32 + 16, 96);
  gemmPF(A00, A10, A01, A11, S1, ca);
  A00 = ldWg(wbf + 16384, 128, 64 + mt * 32, 64);
  A10 = ldWg(wbf + 16384, 128, 64 + mt * 32 + 16, 64);
  A01 = ldWg(wbf + 16384, 128, 64 + mt * 32, 96);
  A11 = ldWg(wbf + 16384, 128, 64 + mt * 32 + 16, 96);
  gemmPF(A00, A10, A01, A11, S1, cb4);
  A00 = ldWg(wbf + 49152, 128, mt * 32, 0);       // issue Wa d-lo k-lo (for P13)
  A10 = ldWg(wbf + 49152, 128, mt * 32 + 16, 0);
  A01 = ldWg(wbf + 49152, 128, mt * 32, 32);
  A11 = ldWg(wbf + 49152, 128, mt * 32 + 16, 32);
  for (int kb = 0; kb < 128; kb += 32) {
    gemmA(S2, ca, kb);
    gemmA(S4, cb4, kb);
  }
  float mw0 = mwt[(size_t)gb * 128 + nn * 32 + c];
  float mw1 = mwt[(size_t)gb * 128 + nn * 32 + 16 + c];
  BARRIER();

  // ==== P11: zero pool/sv1/out slot (counts dead) ====
  if (t < 256) S3f[t] = 0.f;
  if (t == 256) S3f[512] = 0.f;
  BARRIER();

  // ==== P12: BN1+leaky+mw -> h2 (S2/S4, overwriting V1) + pool ====
  {
#pragma unroll
    for (int hf = 0; hf < 2; hf++) {
      f32x4* A = hf ? cb4 : ca;
      unsigned short* H = hf ? S4 : S2;
      int dOff = hf * 64;
#pragma unroll
      for (int i = 0; i < 2; i++) {
        int dB = mt * 32 + 16 * i + r0;
        float4 mul4 = *(const float4*)(cst + 256 + dOff + dB);
        float4 add4 = *(const float4*)(cst + 384 + dOff + dB);
        f32x4 v0v = A[i * 2 + 0], v1v = A[i * 2 + 1];
        float y0 = lk(v0v[0] * mul4.x + add4.x) * mw0;
        float y1 = lk(v0v[1] * mul4.y + add4.y) * mw0;
        float y2 = lk(v0v[2] * mul4.z + add4.z) * mw0;
        float y3 = lk(v0v[3] * mul4.w + add4.w) * mw0;
        float z0 = lk(v1v[0] * mul4.x + add4.x) * mw1;
        float z1 = lk(v1v[1] * mul4.y + add4.y) * mw1;
        float z2 = lk(v1v[2] * mul4.z + add4.z) * mw1;
        float z3 = lk(v1v[3] * mul4.w + add4.w) * mw1;
        int nodeA = nn * 32 + c;
        int nodeB = nn * 32 + 16 + c;
        bf16x4 oa = {(__bf16)y0, (__bf16)y1, (__bf16)y2, (__bf16)y3};
        bf16x4 ob = {(__bf16)z0, (__bf16)z1, (__bf16)z2, (__bf16)z3};
        *(bf16x4*)((char*)H + nodeA * 128 + ((2 * dB) ^ ((nodeA & 7) << 4))) = oa;
        *(bf16x4*)((char*)H + nodeB * 128 + ((2 * dB) ^ ((nodeB & 7) << 4))) = ob;
        float s0 = y0 + z0, s1 = y1 + z1, s2 = y2 + z2, s3 = y3 + z3;
#pragma unroll
        for (int m = 1; m < 16; m <<= 1) {
          s0 += __shfl_xor(s0, m); s1 += __shfl_xor(s1, m);
          s2 += __shfl_xor(s2, m); s3 += __shfl_xor(s3, m);
        }
        if (c == 0) {
          atomicAdd(&S3f[dOff + dB + 0], s0);
          atomicAdd(&S3f[dOff + dB + 1], s1);
          atomicAdd(&S3f[dOff + dB + 2], s2);
          atomicAdd(&S3f[dOff + dB + 3], s3);
        }
      }
    }
  }
  BARRIER();

  // ==== P13: p = Wa@h2 (both halves); +ba leaky -> S0/S1 (h1 dead) ====
#pragma unroll
  for (int i = 0; i < 4; i++) { va[i] = zero; vb[i] = zero; }
  gemmPF(A00, A10, A01, A11, S2, va);
  A00 = ldWg(wbf + 49152, 128, 64 + mt * 32, 0);
  A10 = ldWg(wbf + 49152, 128, 64 + mt * 32 + 16, 0);
  A01 = ldWg(wbf + 49152, 128, 64 + mt * 32, 32);
  A11 = ldWg(wbf + 49152, 128, 64 + mt * 32 + 16, 32);
  gemmPF(A00, A10, A01, A11, S2, vb);
  A00 = ldWg(wbf + 49152, 128, mt * 32, 64);
  A10 = ldWg(wbf + 49152, 128, mt * 32 + 16, 64);
  A01 = ldWg(wbf + 49152, 128, mt * 32, 96);
  A11 = ldWg(wbf + 49152, 128, mt * 32 + 16, 96);
  gemmPF(A00, A10, A01, A11, S4, va);
  A00 = ldWg(wbf + 49152, 128, 64 + mt * 32, 64);
  A10 = ldWg(wbf + 49152, 128, 64 + mt * 32 + 16, 64);
  A01 = ldWg(wbf + 49152, 128, 64 + mt * 32, 96);
  A11 = ldWg(wbf + 49152, 128, 64 + mt * 32 + 16, 96);
  gemmPF(A00, A10, A01, A11, S4, vb);
#pragma unroll
  for (int hf = 0; hf < 2; hf++) {
    f32x4* A = hf ? vb : va;
    unsigned short* H = hf ? S1 : S0;
#pragma unroll
    for (int i = 0; i < 2; i++) {
      int dB = mt * 32 + 16 * i + r0;
      float4 ba4 = *(const float4*)(ba + hf * 64 + dB);
#pragma unroll
      for (int n = 0; n < 2; n++) {
        f32x4 v = A[i * 2 + n];
        int node = nn * 32 + 16 * n + c;
        bf16x4 o = {(__bf16)lk(v[0] + ba4.x), (__bf16)lk(v[1] + ba4.y),
                    (__bf16)lk(v[2] + ba4.z), (__bf16)lk(v[3] + ba4.w)};
        *(bf16x4*)((char*)H + node * 128 + ((2 * dB) ^ ((node & 7) << 4))) = o;
      }
    }
  }
  BARRIER();

  // ==== P15: pair = sigmoid(pA@pB^T) -> row/col sums (sv1 @ S3f+128) ====
  {
    f32x4 acc2[2] = {zero, zero};
    for (int kb = 0; kb < 128; kb += 32) {
      const unsigned short* H = (kb < 64) ? S0 : S1;
      int kl = kb & 63;
#pragma unroll
      for (int i = 0; i < 2; i++) {
        int T = w * 2 + i;
        bf16x8 a = ldH(H, (T >> 2) * 16, kl);
        bf16x8 b = ldH(H, 64 + (T & 3) * 16, kl);
        acc2[i] = MFMA16(a, b, acc2[i]);
      }
    }
    float* sv1 = S3f + 128;
#pragma unroll
    for (int i = 0; i < 2; i++) {
      int T = w * 2 + i, mb = (T >> 2) * 16, nb = (T & 3) * 16;
      float s0 = 1.f / (1.f + __expf(-acc2[i][0]));
      float s1 = 1.f / (1.f + __expf(-acc2[i][1]));
      float s2 = 1.f / (1.f + __expf(-acc2[i][2]));
      float s3 = 1.f / (1.f + __expf(-acc2[i][3]));
      atomicAdd(&sv1[64 + nb + c], s0 + s1 + s2 + s3);
#pragma unroll
      for (int m = 1; m < 16; m <<= 1) {
        s0 += __shfl_xor(s0, m); s1 += __shfl_xor(s1, m);
        s2 += __shfl_xor(s2, m); s3 += __shfl_xor(s3, m);
      }
      if (c < 4) {
        float v = c == 0 ? s0 : (c == 1 ? s1 : (c == 2 ? s2 : s3));
        atomicAdd(&sv1[mb + r0 + c], v);
      }
    }
  }
  BARRIER();

  // ==== P16: delta pool: pool[d] += sum_node u[node]*p[node][d] ====
  {
    int d = t & 127, qd = t >> 7;
    const unsigned short* H = (d < 64) ? S0 : S1;
    int dl2 = (d & 63) * 2;
    float s = 0.f;
#pragma unroll
    for (int i = 0; i < 32; i++) {
      int node = qd * 32 + i;
      float u = S3f[128 + node];
      unsigned short pv = *(const unsigned short*)((const char*)H + node * 128 + (dl2 ^ ((node & 7) << 4)));
      s += u * bf2f(pv);
    }
    atomicAdd(&S3f[d], s);
  }
  BARRIER();

  // ==== P17: readout ====
  if (t < 128) S3f[t] *= (1.f / 128.f);
  BARRIER();
  {
    int d = t >> 2, qd = t & 3;
    const float* row = wr0t + d * 128 + qd * 32;
    float s = 0.f;
#pragma unroll
    for (int j2 = 0; j2 < 32; j2++) s += S3f[qd * 32 + j2] * row[j2];
    s += __shfl_xor(s, 1);
    s += __shfl_xor(s, 2);
    if (qd == 0) { s += br0[d]; S3f[256 + d] = lk(s); }
  }
  BARRIER();
  {
    int d = t >> 2, qd = t & 3;
    const float* row = wr1t + d * 128 + qd * 32;
    float s = 0.f;
#pragma unroll
    for (int j2 = 0; j2 < 32; j2++) s += S3f[256 + qd * 32 + j2] * row[j2];
    s += __shfl_xor(s, 1);
    s += __shfl_xor(s, 2);
    if (qd == 0) { s += br1[d]; S3f[384 + d] = lk(s); }
  }
  BARRIER();
  if (t < 128) atomicAdd(&S3f[512], S3f[384 + t] * Wout[t]);
  BARRIER();
  if (t == 0) out[gb] = S3f[512] + bout[0];
}

extern "C" void kernel_launch(void* const* d_in, const int* in_sizes, int n_in,
                              void* d_out, int out_size, void* d_ws, size_t ws_size,
                              hipStream_t stream) {
  const float* x     = (const float*)d_in[0];
  const float* mwt   = (const float*)d_in[1];
  const float* Wc0s  = (const float*)d_in[2];
  const float* Wc0n  = (const float*)d_in[3];
  const float* bc0   = (const float*)d_in[4];
  const float* g0    = (const float*)d_in[5];
  const float* b0    = (const float*)d_in[6];
  const float* m0    = (const float*)d_in[7];
  const float* v0    = (const float*)d_in[8];
  const float* Wc1s  = (const float*)d_in[9];
  const float* Wc1n  = (const float*)d_in[10];
  const float* bc1   = (const float*)d_in[11];
  const float* g1    = (const float*)d_in[12];
  const float* b1    = (const float*)d_in[13];
  const float* m1    = (const float*)d_in[14];
  const float* v1    = (const float*)d_in[15];
  const float* Wa    = (const float*)d_in[16];
  const float* ba    = (const float*)d_in[17];
  const float* Wr0   = (const float*)d_in[18];
  const float* br0   = (const float*)d_in[19];
  const float* Wr1   = (const float*)d_in[20];
  const float* br1   = (const float*)d_in[21];
  const float* Wout  = (const float*)d_in[22];
  const float* bout  = (const float*)d_in[23];
  const int*   ei    = (const int*)d_in[24];

  unsigned short* wbf = (unsigned short*)d_ws;                 // 131072 B
  float* cst  = (float*)((char*)d_ws + 131072);                // 2048 B
  float* wr0t = (float*)((char*)d_ws + 133120);                // 65536 B
  float* wr1t = (float*)((char*)d_ws + 198656);                // 65536 B

  prep_kernel<<<dim3(225), dim3(256), 0, stream>>>(Wc0s, Wc0n, Wc1s, Wc1n, Wa,
                                                   bc0, g0, b0, m0, v0,
                                                   bc1, g1, b1, m1, v1,
                                                   Wr0, Wr1, wbf, cst, wr0t, wr1t);
  gnn_fused<<<dim3(2048), dim3(512), 0, stream>>>(x, mwt, ei, wbf, cst, ba,
                                                  wr0t, br0, wr1t, br1, Wout, bout,
                                                  (float*)d_out);
}

// Round 10
// 192.278 us; speedup vs baseline: 1.1529x; 1.1084x over previous
//
#include <hip/hip_runtime.h>

#define N_EDGES_C 1048576

typedef __attribute__((ext_vector_type(8))) __bf16 bf16x8;
typedef __attribute__((ext_vector_type(4))) __bf16 bf16x4;
typedef __attribute__((ext_vector_type(4))) float f32x4;

#define MFMA16(a,b,c) __builtin_amdgcn_mfma_f32_16x16x32_bf16((a),(b),(c),0,0,0)

// LDS-visible barrier that does NOT drain vmcnt.
#define BARRIER() do { asm volatile("s_waitcnt lgkmcnt(0)" ::: "memory"); \
                       __builtin_amdgcn_s_barrier(); \
                       asm volatile("" ::: "memory"); } while (0)

__device__ __forceinline__ unsigned short f2bf(float f) {
  unsigned int u = __builtin_bit_cast(unsigned int, f);
  u = (u + 0x7fffu + ((u >> 16) & 1u)) >> 16;
  return (unsigned short)u;
}
__device__ __forceinline__ float bf2f(unsigned short h) {
  unsigned int u = ((unsigned int)h) << 16;
  return __builtin_bit_cast(float, u);
}

// ---------------- prep ----------------
__global__ void prep_kernel(const float* __restrict__ Wc0s, const float* __restrict__ Wc0n,
                            const float* __restrict__ Wc1s, const float* __restrict__ Wc1n,
                            const float* __restrict__ Wa,
                            const float* __restrict__ bc0, const float* __restrict__ g0,
                            const float* __restrict__ b0, const float* __restrict__ m0,
                            const float* __restrict__ v0,
                            const float* __restrict__ bc1, const float* __restrict__ g1,
                            const float* __restrict__ b1, const float* __restrict__ m1,
                            const float* __restrict__ v1,
                            const float* __restrict__ Wr0, const float* __restrict__ Wr1,
                            unsigned short* __restrict__ wbf, float* __restrict__ cst,
                            float* __restrict__ wr0t, float* __restrict__ wr1t) {
  int t = blockIdx.x * blockDim.x + threadIdx.x;
  if (t < 8192) {
    int d = t >> 6, f = t & 63;
    wbf[t]        = f2bf(Wc0s[f * 128 + d]);
    wbf[8192 + t] = f2bf(Wc0n[f * 128 + d]);
  } else if (t < 24576) {
    int i = t - 8192;
    int d = i >> 7, k = i & 127;
    wbf[16384 + i] = f2bf(Wc1s[k * 128 + d]);
    wbf[32768 + i] = f2bf(Wc1n[k * 128 + d]);
    wbf[49152 + i] = f2bf(Wa[k * 128 + d]);
  } else if (t < 24704) {
    int d = t - 24576;
    float s0 = g0[d] * rsqrtf(v0[d] + 1e-5f);
    cst[d]       = s0;
    cst[128 + d] = (bc0[d] - m0[d]) * s0 + b0[d];
    float s1 = g1[d] * rsqrtf(v1[d] + 1e-5f);
    cst[256 + d] = s1;
    cst[384 + d] = (bc1[d] - m1[d]) * s1 + b1[d];
  } else if (t < 57472) {
    int i = t - 24704;
    int which = i >> 14;
    int k = i & 16383;
    int d = k >> 7, j = k & 127;
    float v = (which ? Wr1 : Wr0)[j * 128 + d];
    (which ? wr1t : wr0t)[k] = v;
  }
}

// ---------------- megakernel: 1 block = 1 graph, 80KB arena, 2/CU, 11 barriers ----------------
__global__ __launch_bounds__(512, 4)
void gnn_fused(const float* __restrict__ x, const float* __restrict__ mwt,
               const int* __restrict__ ei,
               const unsigned short* __restrict__ wbf, const float* __restrict__ cst,
               const float* __restrict__ ba,
               float* __restrict__ pooled) {
  __shared__ __align__(16) unsigned char arena[81920];
  unsigned short* S0  = (unsigned short*)(arena);            // V0h0 -> h1h0 -> p_h0
  unsigned short* S1  = (unsigned short*)(arena + 16384);    // V0h1 -> h1h1 -> p_h1
  unsigned short* S2  = (unsigned short*)(arena + 32768);    // invdeg -> V1h0 -> h2h0
  unsigned char*  CNT = arena + 49152;                       // counts -> pool/sv1
  unsigned short* S4  = (unsigned short*)(arena + 65536);    // x -> V1h1 -> h2h1
  float* S2f = (float*)S2;
  float* S3f = (float*)CNT;

  const int gb = blockIdx.x;
  const int t = threadIdx.x;
  const int lane = t & 63;
  const int w = t >> 6;
  const int c  = lane & 15;
  const int gq = lane >> 4;
  const int r0 = gq << 2;
  const int mt = w >> 2;        // d-tile 0..1
  const int nn = w & 3;         // node-tile 0..3
  const f32x4 zero = {0.f, 0.f, 0.f, 0.f};

  auto lk = [](float v) { return v > 0.f ? v : 0.01f * v; };
  auto ldWg = [&](const unsigned short* Wt, int K, int dd, int kb) -> bf16x8 {
    return *(const bf16x8*)(Wt + (dd + c) * K + kb + gq * 8);
  };
  auto ldH = [&](const unsigned short* H, int nodeB, int kl) -> bf16x8 {
    int r = nodeB + c;
    int cb2 = (kl + gq * 8) * 2;
    return *(const bf16x8*)((const char*)H + r * 128 + (cb2 ^ ((r & 7) << 4)));
  };
  auto ldV = [&](const unsigned short* V, int dB, int nodek) -> bf16x8 {
    int r = dB + c;
    int cb2 = (nodek + gq * 8) * 2;
    return *(const bf16x8*)((const char*)V + r * 256 + (cb2 ^ ((r & 7) << 4)));
  };
  auto gemmPF = [&](bf16x8 a00, bf16x8 a10, bf16x8 a01, bf16x8 a11,
                    const unsigned short* H, f32x4* a4) {
    bf16x8 b0 = ldH(H, nn * 32, 0), b1 = ldH(H, nn * 32 + 16, 0);
    a4[0] = MFMA16(a00, b0, a4[0]);
    a4[1] = MFMA16(a00, b1, a4[1]);
    a4[2] = MFMA16(a10, b0, a4[2]);
    a4[3] = MFMA16(a10, b1, a4[3]);
    b0 = ldH(H, nn * 32, 32); b1 = ldH(H, nn * 32 + 16, 32);
    a4[0] = MFMA16(a01, b0, a4[0]);
    a4[1] = MFMA16(a01, b1, a4[1]);
    a4[2] = MFMA16(a11, b0, a4[2]);
    a4[3] = MFMA16(a11, b1, a4[3]);
  };

  // ==== P0: issue W0n-dlo; load edges; zero CNT; x -> S4 ====
  bf16x8 A00 = ldWg(wbf + 8192, 64, mt * 32, 0);
  bf16x8 A10 = ldWg(wbf + 8192, 64, mt * 32 + 16, 0);
  bf16x8 A01 = ldWg(wbf + 8192, 64, mt * 32, 32);
  bf16x8 A11 = ldWg(wbf + 8192, 64, mt * 32 + 16, 32);
  int els, eld;
  {
    int e = gb * 512 + t;
    els = ei[e] & 127;
    eld = ei[N_EDGES_C + e] & 127;
  }
  {
    unsigned int* c32 = (unsigned int*)CNT;
    for (int i = t; i < 4096; i += 512) c32[i] = 0u;
  }
  {
    const float4* xg = (const float4*)(x + (size_t)gb * 8192);
#pragma unroll
    for (int i = 0; i < 4; i++) {
      int vi = t + i * 512;
      float4 v = xg[vi];
      int node = vi >> 4;
      int f2 = (vi & 15) * 8;
      bf16x4 qv = {(__bf16)v.x, (__bf16)v.y, (__bf16)v.z, (__bf16)v.w};
      *(bf16x4*)((char*)S4 + node * 128 + (f2 ^ ((node & 7) << 4))) = qv;
    }
  }
  BARRIER();

  // ==== P1: histogram ====
  {
    int cb = els ^ ((eld & 7) << 3);
    int idx = eld * 128 + cb;
    atomicAdd((unsigned int*)(CNT + (idx & ~3)), 1u << ((idx & 3) * 8));
  }
  BARRIER();

  // ==== P2: inv_deg -> S2f ====
  {
    int row = t >> 2, qd = t & 3;
    const unsigned int* rp = (const unsigned int*)(CNT + row * 128) + qd * 8;
    int ssum = 0;
#pragma unroll
    for (int i = 0; i < 8; i++) {
      unsigned int v = rp[i];
      ssum += (int)(v & 0xff) + (int)((v >> 8) & 0xff) + (int)((v >> 16) & 0xff) + (int)(v >> 24);
    }
    ssum += __shfl_xor(ssum, 1);
    ssum += __shfl_xor(ssum, 2);
    if (qd == 0) S2f[row] = 1.f / (float)(ssum > 1 ? ssum : 1);
  }
  BARRIER();

  const float inv0 = S2f[nn * 32 + c];
  const float inv1 = S2f[nn * 32 + 16 + c];

  auto ldAdj = [&](int noBase, int kb, float inv) -> bf16x8 {
    int m = noBase + c;
    int cc = (kb + gq * 8) ^ ((m & 7) << 3);
    const unsigned int* p = (const unsigned int*)(CNT + m * 128 + cc);
    unsigned int w0 = p[0], w1 = p[1];
    bf16x8 r;
#pragma unroll
    for (int i2 = 0; i2 < 4; i2++) {
      r[i2]     = (__bf16)((float)((w0 >> (8 * i2)) & 0xffu) * inv);
      r[4 + i2] = (__bf16)((float)((w1 >> (8 * i2)) & 0xffu) * inv);
    }
    return r;
  };
  auto gemmA = [&](const unsigned short* V, f32x4* a4, int kb) {
    bf16x8 A0 = ldV(V, mt * 32, kb);
    bf16x8 A1 = ldV(V, mt * 32 + 16, kb);
    bf16x8 B0 = ldAdj(nn * 32, kb, inv0);
    bf16x8 B1 = ldAdj(nn * 32 + 16, kb, inv1);
    a4[0] = MFMA16(A0, B0, a4[0]);
    a4[1] = MFMA16(A0, B1, a4[1]);
    a4[2] = MFMA16(A1, B0, a4[2]);
    a4[3] = MFMA16(A1, B1, a4[3]);
  };
  auto epiV = [&](unsigned short* V, f32x4* av) {
#pragma unroll
    for (int i = 0; i < 2; i++)
#pragma unroll
      for (int n = 0; n < 2; n++) {
        f32x4 v = av[i * 2 + n];
        float a0 = v[0], a1 = v[1], a2 = v[2], a3 = v[3];
        {
          bool lo = (lane & 1) == 0;
          float sA = lo ? a1 : a0, sB = lo ? a3 : a2;
          float rA = __shfl_xor(sA, 1), rB = __shfl_xor(sB, 1);
          if (lo) { a1 = rA; a3 = rB; } else { a0 = rA; a2 = rB; }
        }
        {
          bool lo = (lane & 2) == 0;
          float sA = lo ? a2 : a0, sB = lo ? a3 : a1;
          float rA = __shfl_xor(sA, 2), rB = __shfl_xor(sB, 2);
          if (lo) { a2 = rA; a3 = rB; } else { a0 = rA; a1 = rB; }
        }
        int dloc = mt * 32 + 16 * i + r0 + (lane & 3);
        int nodeB2 = (nn * 32 + 16 * n + ((lane >> 2) & 3) * 4) * 2;
        bf16x4 o = {(__bf16)a0, (__bf16)a1, (__bf16)a2, (__bf16)a3};
        *(bf16x4*)((char*)V + dloc * 256 + (nodeB2 ^ ((dloc & 7) << 4))) = o;
      }
  };
  // feature-layout epilogue write: acc^T[d][node] -> H[node][dhalf]
  auto epiF = [&](unsigned short* H, f32x4* A, const float* mul0, const float* add0,
                  bool bn, float mwa, float mwb) {
#pragma unroll
    for (int i = 0; i < 2; i++) {
      int dB = mt * 32 + 16 * i + r0;
      float4 mul4 = bn ? *(const float4*)(mul0 + dB) : float4{0, 0, 0, 0};
      float4 add4 = *(const float4*)(add0 + dB);
#pragma unroll
      for (int n = 0; n < 2; n++) {
        f32x4 v = A[i * 2 + n];
        float mw = n ? mwb : mwa;
        int node = nn * 32 + 16 * n + c;
        bf16x4 o;
        if (bn) {
          o = bf16x4{(__bf16)(lk(v[0] * mul4.x + add4.x) * mw),
                     (__bf16)(lk(v[1] * mul4.y + add4.y) * mw),
                     (__bf16)(lk(v[2] * mul4.z + add4.z) * mw),
                     (__bf16)(lk(v[3] * mul4.w + add4.w) * mw)};
        } else {
          o = bf16x4{(__bf16)lk(v[0] + add4.x), (__bf16)lk(v[1] + add4.y),
                     (__bf16)lk(v[2] + add4.z), (__bf16)lk(v[3] + add4.w)};
        }
        *(bf16x4*)((char*)H + node * 128 + ((2 * dB) ^ ((node & 7) << 4))) = o;
      }
    }
  };

  f32x4 va[4], vb[4], ca[4], cb4[4];
  bf16x8 B00, B10, B01, B11;

  // ==== P3: V0 full = W0n@x; epiV -> S0,S1; issue W0s-dlo ====
#pragma unroll
  for (int i = 0; i < 4; i++) { va[i] = zero; vb[i] = zero; }
  gemmPF(A00, A10, A01, A11, S4, va);                 // dlo
  B00 = ldWg(wbf + 8192, 64, 64 + mt * 32, 0);        // dhi
  B10 = ldWg(wbf + 8192, 64, 64 + mt * 32 + 16, 0);
  B01 = ldWg(wbf + 8192, 64, 64 + mt * 32, 32);
  B11 = ldWg(wbf + 8192, 64, 64 + mt * 32 + 16, 32);
  gemmPF(B00, B10, B01, B11, S4, vb);
  A00 = ldWg(wbf, 64, mt * 32, 0);                    // W0s dlo (for P4)
  A10 = ldWg(wbf, 64, mt * 32 + 16, 0);
  A01 = ldWg(wbf, 64, mt * 32, 32);
  A11 = ldWg(wbf, 64, mt * 32 + 16, 32);
  epiV(S0, va);
  epiV(S1, vb);
  BARRIER();

  // ==== P4: conv0 full = Adj@V0 (first, covers W loads) + W0s@x ====
#pragma unroll
  for (int i = 0; i < 4; i++) { ca[i] = zero; cb4[i] = zero; }
  B00 = ldWg(wbf, 64, 64 + mt * 32, 0);               // W0s dhi
  B10 = ldWg(wbf, 64, 64 + mt * 32 + 16, 0);
  B01 = ldWg(wbf, 64, 64 + mt * 32, 32);
  B11 = ldWg(wbf, 64, 64 + mt * 32 + 16, 32);
  for (int kb = 0; kb < 128; kb += 32) {
    gemmA(S0, ca, kb);
    gemmA(S1, cb4, kb);
  }
  gemmPF(A00, A10, A01, A11, S4, ca);
  gemmPF(B00, B10, B01, B11, S4, cb4);
  BARRIER();

  // ==== P5: BN0 epi -> h1 (S0,S1); issue W1n dlo-klo ====
  A00 = ldWg(wbf + 32768, 128, mt * 32, 0);
  A10 = ldWg(wbf + 32768, 128, mt * 32 + 16, 0);
  A01 = ldWg(wbf + 32768, 128, mt * 32, 32);
  A11 = ldWg(wbf + 32768, 128, mt * 32 + 16, 32);
  epiF(S0, ca, cst, cst + 128, true, 1.f, 1.f);
  epiF(S1, cb4, cst + 64, cst + 192, true, 1.f, 1.f);
  BARRIER();

  // ==== P6: V1 full (K=128); epiV -> S2,S4; issue W1s dlo-klo ====
#pragma unroll
  for (int i = 0; i < 4; i++) { va[i] = zero; vb[i] = zero; }
  gemmPF(A00, A10, A01, A11, S0, va);                 // dlo klo
  B00 = ldWg(wbf + 32768, 128, 64 + mt * 32, 0);
  B10 = ldWg(wbf + 32768, 128, 64 + mt * 32 + 16, 0);
  B01 = ldWg(wbf + 32768, 128, 64 + mt * 32, 32);
  B11 = ldWg(wbf + 32768, 128, 64 + mt * 32 + 16, 32);
  gemmPF(B00, B10, B01, B11, S0, vb);                 // dhi klo
  A00 = ldWg(wbf + 32768, 128, mt * 32, 64);
  A10 = ldWg(wbf + 32768, 128, mt * 32 + 16, 64);
  A01 = ldWg(wbf + 32768, 128, mt * 32, 96);
  A11 = ldWg(wbf + 32768, 128, mt * 32 + 16, 96);
  gemmPF(A00, A10, A01, A11, S1, va);                 // dlo khi
  B00 = ldWg(wbf + 32768, 128, 64 + mt * 32, 64);
  B10 = ldWg(wbf + 32768, 128, 64 + mt * 32 + 16, 64);
  B01 = ldWg(wbf + 32768, 128, 64 + mt * 32, 96);
  B11 = ldWg(wbf + 32768, 128, 64 + mt * 32 + 16, 96);
  gemmPF(B00, B10, B01, B11, S1, vb);                 // dhi khi
  A00 = ldWg(wbf + 16384, 128, mt * 32, 0);           // W1s dlo klo (P7)
  A10 = ldWg(wbf + 16384, 128, mt * 32 + 16, 0);
  A01 = ldWg(wbf + 16384, 128, mt * 32, 32);
  A11 = ldWg(wbf + 16384, 128, mt * 32 + 16, 32);
  epiV(S2, va);
  epiV(S4, vb);
  BARRIER();

  // ==== P7: conv1 full = Adj@V1 (first) + W1s@h1 ====
#pragma unroll
  for (int i = 0; i < 4; i++) { ca[i] = zero; cb4[i] = zero; }
  for (int kb = 0; kb < 128; kb += 32) {
    gemmA(S2, ca, kb);
    gemmA(S4, cb4, kb);
  }
  gemmPF(A00, A10, A01, A11, S0, ca);                 // dlo klo
  B00 = ldWg(wbf + 16384, 128, 64 + mt * 32, 0);
  B10 = ldWg(wbf + 16384, 128, 64 + mt * 32 + 16, 0);
  B01 = ldWg(wbf + 16384, 128, 64 + mt * 32, 32);
  B11 = ldWg(wbf + 16384, 128, 64 + mt * 32 + 16, 32);
  gemmPF(B00, B10, B01, B11, S0, cb4);                // dhi klo
  A00 = ldWg(wbf + 16384, 128, mt * 32, 64);
  A10 = ldWg(wbf + 16384, 128, mt * 32 + 16, 64);
  A01 = ldWg(wbf + 16384, 128, mt * 32, 96);
  A11 = ldWg(wbf + 16384, 128, mt * 32 + 16, 96);
  gemmPF(A00, A10, A01, A11, S1, ca);                 // dlo khi
  B00 = ldWg(wbf + 16384, 128, 64 + mt * 32, 64);
  B10 = ldWg(wbf + 16384, 128, 64 + mt * 32 + 16, 64);
  B01 = ldWg(wbf + 16384, 128, 64 + mt * 32, 96);
  B11 = ldWg(wbf + 16384, 128, 64 + mt * 32 + 16, 96);
  gemmPF(B00, B10, B01, B11, S1, cb4);                // dhi khi
  float mw0 = mwt[(size_t)gb * 128 + nn * 32 + c];
  float mw1 = mwt[(size_t)gb * 128 + nn * 32 + 16 + c];
  BARRIER();

  // ==== P8: BN1 epi -> h2 (S2,S4); zero S3f; issue Wa dlo-klo ====
  A00 = ldWg(wbf + 49152, 128, mt * 32, 0);
  A10 = ldWg(wbf + 49152, 128, mt * 32 + 16, 0);
  A01 = ldWg(wbf + 49152, 128, mt * 32, 32);
  A11 = ldWg(wbf + 49152, 128, mt * 32 + 16, 32);
  epiF(S2, ca, cst + 256, cst + 384, true, mw0, mw1);
  epiF(S4, cb4, cst + 320, cst + 448, true, mw0, mw1);
  if (t < 256) S3f[t] = 0.f;
  BARRIER();

  // ==== P9: p full = Wa@h2; +ba leaky epi -> S0,S1 ====
#pragma unroll
  for (int i = 0; i < 4; i++) { va[i] = zero; vb[i] = zero; }
  gemmPF(A00, A10, A01, A11, S2, va);
  B00 = ldWg(wbf + 49152, 128, 64 + mt * 32, 0);
  B10 = ldWg(wbf + 49152, 128, 64 + mt * 32 + 16, 0);
  B01 = ldWg(wbf + 49152, 128, 64 + mt * 32, 32);
  B11 = ldWg(wbf + 49152, 128, 64 + mt * 32 + 16, 32);
  gemmPF(B00, B10, B01, B11, S2, vb);
  A00 = ldWg(wbf + 49152, 128, mt * 32, 64);
  A10 = ldWg(wbf + 49152, 128, mt * 32 + 16, 64);
  A01 = ldWg(wbf + 49152, 128, mt * 32, 96);
  A11 = ldWg(wbf + 49152, 128, mt * 32 + 16, 96);
  gemmPF(A00, A10, A01, A11, S4, va);
  B00 = ldWg(wbf + 49152, 128, 64 + mt * 32, 64);
  B10 = ldWg(wbf + 49152, 128, 64 + mt * 32 + 16, 64);
  B01 = ldWg(wbf + 49152, 128, 64 + mt * 32, 96);
  B11 = ldWg(wbf + 49152, 128, 64 + mt * 32 + 16, 96);
  gemmPF(B00, B10, B01, B11, S4, vb);
  epiF(S0, va, nullptr, ba, false, 1.f, 1.f);
  epiF(S1, vb, nullptr, ba + 64, false, 1.f, 1.f);
  BARRIER();

  // ==== P10: pair = sigmoid(pA@pB^T) -> row/col sums (sv1 @ S3f+128) ====
  {
    f32x4 acc2[2] = {zero, zero};
    for (int kb = 0; kb < 128; kb += 32) {
      const unsigned short* H = (kb < 64) ? S0 : S1;
      int kl = kb & 63;
#pragma unroll
      for (int i = 0; i < 2; i++) {
        int T = w * 2 + i;
        bf16x8 a = ldH(H, (T >> 2) * 16, kl);
        bf16x8 b = ldH(H, 64 + (T & 3) * 16, kl);
        acc2[i] = MFMA16(a, b, acc2[i]);
      }
    }
    float* sv1 = S3f + 128;
#pragma unroll
    for (int i = 0; i < 2; i++) {
      int T = w * 2 + i, mb = (T >> 2) * 16, nb = (T & 3) * 16;
      float s0 = 1.f / (1.f + __expf(-acc2[i][0]));
      float s1 = 1.f / (1.f + __expf(-acc2[i][1]));
      float s2 = 1.f / (1.f + __expf(-acc2[i][2]));
      float s3 = 1.f / (1.f + __expf(-acc2[i][3]));
      atomicAdd(&sv1[64 + nb + c], s0 + s1 + s2 + s3);
#pragma unroll
      for (int m = 1; m < 16; m <<= 1) {
        s0 += __shfl_xor(s0, m); s1 += __shfl_xor(s1, m);
        s2 += __shfl_xor(s2, m); s3 += __shfl_xor(s3, m);
      }
      if (c < 4) {
        float v = c == 0 ? s0 : (c == 1 ? s1 : (c == 2 ? s2 : s3));
        atomicAdd(&sv1[mb + r0 + c], v);
      }
    }
  }
  BARRIER();

  // ==== P11: pool[d] = sum_node (u[node]*p[node][d] + h2[node][d]) ====
  {
    int d = t & 127, qd = t >> 7;
    const unsigned short* Hp = (d < 64) ? S0 : S1;
    const unsigned short* Hh = (d < 64) ? S2 : S4;
    int dl2 = (d & 63) * 2;
    float s = 0.f;
#pragma unroll
    for (int i = 0; i < 32; i++) {
      int node = qd * 32 + i;
      float u = S3f[128 + node];
      int off = dl2 ^ ((node & 7) << 4);
      float pv = bf2f(*(const unsigned short*)((const char*)Hp + node * 128 + off));
      float hv = bf2f(*(const unsigned short*)((const char*)Hh + node * 128 + off));
      s += u * pv + hv;
    }
    atomicAdd(&S3f[d], s);
  }
  BARRIER();

  // ==== P12: write pooled mean ====
  if (t < 128) pooled[(size_t)gb * 128 + t] = S3f[t] * (1.f / 128.f);
}

// ---------------- readout: r = leaky(leaky(pooled@Wr0+br0)@Wr1+br1)@Wout + bout ----------------
__global__ __launch_bounds__(128)
void readout_kernel(const float* __restrict__ pooled,
                    const float* __restrict__ wr0t, const float* __restrict__ br0,
                    const float* __restrict__ wr1t, const float* __restrict__ br1,
                    const float* __restrict__ Wout, const float* __restrict__ bout,
                    float* __restrict__ out) {
  __shared__ float pl[128], t1[128];
  __shared__ float sred[2];
  int g = blockIdx.x, t = threadIdx.x;
  pl[t] = pooled[(size_t)g * 128 + t];
  __syncthreads();
  {
    const float* row = wr0t + t * 128;
    float s = 0.f;
#pragma unroll 8
    for (int j = 0; j < 128; j++) s += pl[j] * row[j];
    s += br0[t];
    t1[t] = s > 0.f ? s : 0.01f * s;
  }
  __syncthreads();
  float v2;
  {
    const float* row = wr1t + t * 128;
    float s = 0.f;
#pragma unroll 8
    for (int j = 0; j < 128; j++) s += t1[j] * row[j];
    s += br1[t];
    s = s > 0.f ? s : 0.01f * s;
    v2 = s * Wout[t];
  }
#pragma unroll
  for (int m = 1; m < 64; m <<= 1) v2 += __shfl_xor(v2, m);
  if ((t & 63) == 0) sred[t >> 6] = v2;
  __syncthreads();
  if (t == 0) out[g] = sred[0] + sred[1] + bout[0];
}

extern "C" void kernel_launch(void* const* d_in, const int* in_sizes, int n_in,
                              void* d_out, int out_size, void* d_ws, size_t ws_size,
                              hipStream_t stream) {
  const float* x     = (const float*)d_in[0];
  const float* mwt   = (const float*)d_in[1];
  const float* Wc0s  = (const float*)d_in[2];
  const float* Wc0n  = (const float*)d_in[3];
  const float* bc0   = (const float*)d_in[4];
  const float* g0    = (const float*)d_in[5];
  const float* b0    = (const float*)d_in[6];
  const float* m0    = (const float*)d_in[7];
  const float* v0    = (const float*)d_in[8];
  const float* Wc1s  = (const float*)d_in[9];
  const float* Wc1n  = (const float*)d_in[10];
  const float* bc1   = (const float*)d_in[11];
  const float* g1    = (const float*)d_in[12];
  const float* b1    = (const float*)d_in[13];
  const float* m1    = (const float*)d_in[14];
  const float* v1    = (const float*)d_in[15];
  const float* Wa    = (const float*)d_in[16];
  const float* ba    = (const float*)d_in[17];
  const float* Wr0   = (const float*)d_in[18];
  const float* br0   = (const float*)d_in[19];
  const float* Wr1   = (const float*)d_in[20];
  const float* br1   = (const float*)d_in[21];
  const float* Wout  = (const float*)d_in[22];
  const float* bout  = (const float*)d_in[23];
  const int*   ei    = (const int*)d_in[24];

  unsigned short* wbf = (unsigned short*)d_ws;                 // 131072 B
  float* cst    = (float*)((char*)d_ws + 131072);              // 2048 B
  float* wr0t   = (float*)((char*)d_ws + 133120);              // 65536 B
  float* wr1t   = (float*)((char*)d_ws + 198656);              // 65536 B
  float* pooled = (float*)((char*)d_ws + 264192);              // 1048576 B

  prep_kernel<<<dim3(225), dim3(256), 0, stream>>>(Wc0s, Wc0n, Wc1s, Wc1n, Wa,
                                                   bc0, g0, b0, m0, v0,
                                                   bc1, g1, b1, m1, v1,
                                                   Wr0, Wr1, wbf, cst, wr0t, wr1t);
  gnn_fused<<<dim3(2048), dim3(512), 0, stream>>>(x, mwt, ei, wbf, cst, ba, pooled);
  readout_kernel<<<dim3(2048), dim3(128), 0, stream>>>(pooled, wr0t, br0, wr1t, br1,
                                                       Wout, bout, (float*)d_out);
}